// Round 7
// baseline (1820.202 us; speedup 1.0000x reference)
//
#include <hip/hip_runtime.h>

// TAGConv: N=50000, E=800000, F=64, OUT=64, K=3.
// Round 7: gemm with double-buffered W (1 barrier/stage) + batched h[16]
// loads (16 loads in flight); XCD-partitioned count_rows.

#define F 64
#define OUT 64
#define SCAN_ELEMS 1024
#define NPART 8

// XCD-partitioned counting (atomics on counts stay within one XCD's L2).
__global__ __launch_bounds__(256) void count_part(
    const int* __restrict__ row, int* __restrict__ counts, int E, int rpp) {
  int part = blockIdx.x & (NPART - 1);
  int e = (blockIdx.x >> 3) * 256 + threadIdx.x;
  if (e >= E) return;
  int r = row[e];
  if ((unsigned)(r - part * rpp) >= (unsigned)rpp) return;
  atomicAdd(&counts[r], 1);
}

__global__ __launch_bounds__(256) void block_scan(
    const int* __restrict__ counts, int* __restrict__ offsets,
    int* __restrict__ blockSums, int N) {
  __shared__ int s[256];
  int t = threadIdx.x;
  int base = blockIdx.x * SCAN_ELEMS + t * 4;
  int v0 = 0, v1 = 0, v2 = 0, v3 = 0;
  if (base + 3 < N) {
    int4 c = *(const int4*)&counts[base];
    v0 = c.x; v1 = c.y; v2 = c.z; v3 = c.w;
  } else {
    if (base < N)     v0 = counts[base];
    if (base + 1 < N) v1 = counts[base + 1];
    if (base + 2 < N) v2 = counts[base + 2];
  }
  s[t] = v0 + v1 + v2 + v3;
  __syncthreads();
  for (int d = 1; d < 256; d <<= 1) {
    int x = (t >= d) ? s[t - d] : 0;
    __syncthreads();
    s[t] += x;
    __syncthreads();
  }
  int ex = (t == 0) ? 0 : s[t - 1];
  if (t == 255) blockSums[blockIdx.x] = s[255];
  int o0 = ex, o1 = o0 + v0, o2 = o1 + v1, o3 = o2 + v2;
  if (base + 3 < N) {
    *(int4*)&offsets[base] = make_int4(o0, o1, o2, o3);
  } else {
    if (base < N)     offsets[base]     = o0;
    if (base + 1 < N) offsets[base + 1] = o1;
    if (base + 2 < N) offsets[base + 2] = o2;
  }
}

__global__ __launch_bounds__(64) void scan_sums(int* __restrict__ blockSums, int nb) {
  int lane = threadIdx.x;
  if (nb <= 64) {
    int v = (lane < nb) ? blockSums[lane] : 0;
    int incl = v;
    for (int d = 1; d < 64; d <<= 1) {
      int u = __shfl_up(incl, d, 64);
      if (lane >= d) incl += u;
    }
    if (lane < nb) blockSums[lane] = incl - v;
  } else if (lane == 0) {
    int run = 0;
    for (int i = 0; i < nb; ++i) { int c = blockSums[i]; blockSums[i] = run; run += c; }
  }
}

__global__ __launch_bounds__(256) void add_offsets(
    int* __restrict__ offsets, const int* __restrict__ blockSums,
    int* __restrict__ cursor, int N, int E) {
  int i = blockIdx.x * 256 + threadIdx.x;
  if (i < N) {
    int o = offsets[i] + blockSums[i >> 10];
    offsets[i] = o;
    cursor[i] = o;
  }
  if (i == 0) offsets[N] = E;
}

// XCD-partitioned scatter: recs lines written by one XCD's L2.
__global__ __launch_bounds__(256) void scatter_part(
    const int* __restrict__ row, const int* __restrict__ col,
    const float* __restrict__ val, int* __restrict__ cursor,
    float2* __restrict__ recs, int E, int rpp) {
  int part = blockIdx.x & (NPART - 1);
  int e = (blockIdx.x >> 3) * 256 + threadIdx.x;
  if (e >= E) return;
  int r = row[e];
  unsigned lo = (unsigned)(part * rpp);
  if ((unsigned)(r - lo) >= (unsigned)rpp) return;
  int p = atomicAdd(&cursor[r], 1);
  recs[p] = make_float2(__int_as_float(col[e]), val[e]);
}

// 16-lane group per row; lane owns 4 features.
__global__ __launch_bounds__(256) void spmm_g16(
    const int* __restrict__ off, const float2* __restrict__ recs,
    const float* __restrict__ hin, float* __restrict__ hout, int N) {
  int r = (blockIdx.x * 256 + threadIdx.x) >> 4;
  if (r >= N) return;
  int fp = (threadIdx.x & 15) << 2;
  int i = off[r], end = off[r + 1];
  float4 acc = make_float4(0.f, 0.f, 0.f, 0.f);

  for (; i + 4 <= end; i += 4) {
    float2 e0 = recs[i], e1 = recs[i + 1], e2 = recs[i + 2], e3 = recs[i + 3];
    float4 h0 = *(const float4*)&hin[(size_t)__float_as_int(e0.x) * F + fp];
    float4 h1 = *(const float4*)&hin[(size_t)__float_as_int(e1.x) * F + fp];
    float4 h2 = *(const float4*)&hin[(size_t)__float_as_int(e2.x) * F + fp];
    float4 h3 = *(const float4*)&hin[(size_t)__float_as_int(e3.x) * F + fp];
    acc.x = fmaf(e0.y, h0.x, acc.x); acc.y = fmaf(e0.y, h0.y, acc.y);
    acc.z = fmaf(e0.y, h0.z, acc.z); acc.w = fmaf(e0.y, h0.w, acc.w);
    acc.x = fmaf(e1.y, h1.x, acc.x); acc.y = fmaf(e1.y, h1.y, acc.y);
    acc.z = fmaf(e1.y, h1.z, acc.z); acc.w = fmaf(e1.y, h1.w, acc.w);
    acc.x = fmaf(e2.y, h2.x, acc.x); acc.y = fmaf(e2.y, h2.y, acc.y);
    acc.z = fmaf(e2.y, h2.z, acc.z); acc.w = fmaf(e2.y, h2.w, acc.w);
    acc.x = fmaf(e3.y, h3.x, acc.x); acc.y = fmaf(e3.y, h3.y, acc.y);
    acc.z = fmaf(e3.y, h3.z, acc.z); acc.w = fmaf(e3.y, h3.w, acc.w);
  }
  for (; i < end; ++i) {
    float2 e0 = recs[i];
    float4 h0 = *(const float4*)&hin[(size_t)__float_as_int(e0.x) * F + fp];
    acc.x = fmaf(e0.y, h0.x, acc.x); acc.y = fmaf(e0.y, h0.y, acc.y);
    acc.z = fmaf(e0.y, h0.z, acc.z); acc.w = fmaf(e0.y, h0.w, acc.w);
  }
  *(float4*)&hout[(size_t)r * F + fp] = acc;
}

// out = bias + h0@W0 + h1@W1 + h2@W2 + h3@W3 (h3 lives in out).
// Double-buffered W in LDS (1 barrier/stage), batched h[16] register loads.
__global__ __launch_bounds__(256) void gemm_fused4_v3(
    const float* __restrict__ h0, const float* __restrict__ h1,
    const float* __restrict__ h2, const float* __restrict__ W,
    const float* __restrict__ bias, float* __restrict__ out, int N) {
  __shared__ float Ws[2][64 * 64];  // 32 KB ping-pong
  const float* hs[4] = {h0, h1, h2, out};

  int t = threadIdx.x;
  int nl = t >> 2;
  int oq = t & 3;
  int og = oq << 4;
  int node = blockIdx.x * 64 + nl;
  int nodec = min(node, N - 1);

  // fill buf0 with W0 (vectorized)
  {
    const float4* Wg = (const float4*)W;
    float4* Wd = (float4*)Ws[0];
#pragma unroll
    for (int i = 0; i < 4; ++i) Wd[t + i * 256] = Wg[t + i * 256];
  }

  const float4* b4 = (const float4*)bias;
  float4 a0 = b4[oq * 4 + 0], a1 = b4[oq * 4 + 1],
         a2 = b4[oq * 4 + 2], a3 = b4[oq * 4 + 3];

#pragma unroll
  for (int s = 0; s < 4; ++s) {
    __syncthreads();  // buf[s&1] ready; stage s-1 readers of buf[(s+1)&1] done

    // prefetch next stage's W into registers (latency hides under compute)
    float4 wn0, wn1, wn2, wn3;
    if (s < 3) {
      const float4* Wg = (const float4*)(W + (s + 1) * 4096);
      wn0 = Wg[t]; wn1 = Wg[t + 256]; wn2 = Wg[t + 512]; wn3 = Wg[t + 768];
    }

    // batched h-row load: 16 independent float4 loads in flight
    const float4* hrow = (const float4*)(hs[s] + (size_t)nodec * F);
    float4 h[16];
#pragma unroll
    for (int i = 0; i < 16; ++i) h[i] = hrow[i];

    const float* Wb = Ws[s & 1];
#pragma unroll
    for (int k4 = 0; k4 < 16; ++k4) {
      float hk0 = h[k4].x, hk1 = h[k4].y, hk2 = h[k4].z, hk3 = h[k4].w;
#pragma unroll
      for (int j = 0; j < 4; ++j) {
        float hv = (j == 0) ? hk0 : (j == 1) ? hk1 : (j == 2) ? hk2 : hk3;
        const float4* w4 = (const float4*)&Wb[(k4 * 4 + j) * 64 + og];
        float4 w0 = w4[0], w1 = w4[1], w2 = w4[2], w3 = w4[3];
        a0.x = fmaf(hv, w0.x, a0.x); a0.y = fmaf(hv, w0.y, a0.y);
        a0.z = fmaf(hv, w0.z, a0.z); a0.w = fmaf(hv, w0.w, a0.w);
        a1.x = fmaf(hv, w1.x, a1.x); a1.y = fmaf(hv, w1.y, a1.y);
        a1.z = fmaf(hv, w1.z, a1.z); a1.w = fmaf(hv, w1.w, a1.w);
        a2.x = fmaf(hv, w2.x, a2.x); a2.y = fmaf(hv, w2.y, a2.y);
        a2.z = fmaf(hv, w2.z, a2.z); a2.w = fmaf(hv, w2.w, a2.w);
        a3.x = fmaf(hv, w3.x, a3.x); a3.y = fmaf(hv, w3.y, a3.y);
        a3.z = fmaf(hv, w3.z, a3.z); a3.w = fmaf(hv, w3.w, a3.w);
      }
    }

    // store prefetched W to the other buffer (safe: last touch of that
    // buffer was stage s-1 reads, already behind this stage's barrier)
    if (s < 3) {
      float4* Wd = (float4*)Ws[(s + 1) & 1];
      Wd[t] = wn0; Wd[t + 256] = wn1; Wd[t + 512] = wn2; Wd[t + 768] = wn3;
    }
  }

  if (node < N) {
    float4* o4 = (float4*)&out[(size_t)node * OUT + og];
    o4[0] = a0; o4[1] = a1; o4[2] = a2; o4[3] = a3;
  }
}

extern "C" void kernel_launch(void* const* d_in, const int* in_sizes, int n_in,
                              void* d_out, int out_size, void* d_ws, size_t ws_size,
                              hipStream_t stream) {
  const float* x    = (const float*)d_in[0];
  const int*   erow = (const int*)d_in[1];
  const int*   ecol = (const int*)d_in[2];
  const float* eval = (const float*)d_in[3];
  const float* W    = (const float*)d_in[4];
  const float* b    = (const float*)d_in[5];
  float* out = (float*)d_out;

  int N = in_sizes[0] / F;
  int E = in_sizes[1];
  size_t SZ = (size_t)N * F * sizeof(float);
  int nScanBlocks = (N + SCAN_ELEMS - 1) / SCAN_ELEMS;
  int rpp = (N + NPART - 1) / NPART;

  char* p = (char*)d_ws;
  float*  hA     = (float*)p;  p += SZ;
  float*  hB     = (float*)p;  p += SZ;
  float2* recs   = (float2*)p; p += (size_t)E * sizeof(float2);
  int*    counts = (int*)p;    p += (size_t)N * sizeof(int);
  int*    offs   = (int*)p;    p += (size_t)(N + 1) * sizeof(int);
  int*    cursor = (int*)p;    p += (size_t)N * sizeof(int);
  int*    bsums  = (int*)p;    p += (size_t)nScanBlocks * sizeof(int);

  int egrid = (E + 255) / 256;
  int g16grid = ((size_t)N * 16 + 255) / 256;
  int ggrid = (N + 63) / 64;

  // --- CSR build ---
  hipMemsetAsync(counts, 0, (size_t)N * sizeof(int), stream);
  count_part<<<egrid * NPART, 256, 0, stream>>>(erow, counts, E, rpp);
  block_scan<<<nScanBlocks, 256, 0, stream>>>(counts, offs, bsums, N);
  scan_sums<<<1, 64, 0, stream>>>(bsums, nScanBlocks);
  add_offsets<<<(N + 255) / 256, 256, 0, stream>>>(offs, bsums, cursor, N, E);
  scatter_part<<<egrid * NPART, 256, 0, stream>>>(erow, ecol, eval, cursor, recs, E, rpp);

  // --- propagation (h3 -> d_out as scratch) ---
  spmm_g16<<<g16grid, 256, 0, stream>>>(offs, recs, x, hA, N);    // h1
  spmm_g16<<<g16grid, 256, 0, stream>>>(offs, recs, hA, hB, N);   // h2
  spmm_g16<<<g16grid, 256, 0, stream>>>(offs, recs, hB, out, N);  // h3

  gemm_fused4_v3<<<ggrid, 256, 0, stream>>>(x, hA, hB, W, b, out, N);
}

// Round 8
// 213.553 us; speedup vs baseline: 8.5234x; 8.5234x over previous
//
#include <hip/hip_runtime.h>

// TAGConv: N=50000, E=800000, F=64, OUT=64, K=3.
// Round 8: gemm v4 — 4 nodes/thread so W LDS reads are reused 4x
// (0.25 LDS floats per FMA, compute-bound); explicit 1-ahead h pipeline,
// #pragma unroll 2 to prevent load hoisting (v3 spill lesson).

#define F 64
#define OUT 64
#define SCAN_ELEMS 1024
#define NPART 8

__global__ __launch_bounds__(256) void count_part(
    const int* __restrict__ row, int* __restrict__ counts, int E, int rpp) {
  int part = blockIdx.x & (NPART - 1);
  int e = (blockIdx.x >> 3) * 256 + threadIdx.x;
  if (e >= E) return;
  int r = row[e];
  if ((unsigned)(r - part * rpp) >= (unsigned)rpp) return;
  atomicAdd(&counts[r], 1);
}

__global__ __launch_bounds__(256) void block_scan(
    const int* __restrict__ counts, int* __restrict__ offsets,
    int* __restrict__ blockSums, int N) {
  __shared__ int s[256];
  int t = threadIdx.x;
  int base = blockIdx.x * SCAN_ELEMS + t * 4;
  int v0 = 0, v1 = 0, v2 = 0, v3 = 0;
  if (base + 3 < N) {
    int4 c = *(const int4*)&counts[base];
    v0 = c.x; v1 = c.y; v2 = c.z; v3 = c.w;
  } else {
    if (base < N)     v0 = counts[base];
    if (base + 1 < N) v1 = counts[base + 1];
    if (base + 2 < N) v2 = counts[base + 2];
  }
  s[t] = v0 + v1 + v2 + v3;
  __syncthreads();
  for (int d = 1; d < 256; d <<= 1) {
    int x = (t >= d) ? s[t - d] : 0;
    __syncthreads();
    s[t] += x;
    __syncthreads();
  }
  int ex = (t == 0) ? 0 : s[t - 1];
  if (t == 255) blockSums[blockIdx.x] = s[255];
  int o0 = ex, o1 = o0 + v0, o2 = o1 + v1, o3 = o2 + v2;
  if (base + 3 < N) {
    *(int4*)&offsets[base] = make_int4(o0, o1, o2, o3);
  } else {
    if (base < N)     offsets[base]     = o0;
    if (base + 1 < N) offsets[base + 1] = o1;
    if (base + 2 < N) offsets[base + 2] = o2;
  }
}

__global__ __launch_bounds__(64) void scan_sums(int* __restrict__ blockSums, int nb) {
  int lane = threadIdx.x;
  if (nb <= 64) {
    int v = (lane < nb) ? blockSums[lane] : 0;
    int incl = v;
    for (int d = 1; d < 64; d <<= 1) {
      int u = __shfl_up(incl, d, 64);
      if (lane >= d) incl += u;
    }
    if (lane < nb) blockSums[lane] = incl - v;
  } else if (lane == 0) {
    int run = 0;
    for (int i = 0; i < nb; ++i) { int c = blockSums[i]; blockSums[i] = run; run += c; }
  }
}

__global__ __launch_bounds__(256) void add_offsets(
    int* __restrict__ offsets, const int* __restrict__ blockSums,
    int* __restrict__ cursor, int N, int E) {
  int i = blockIdx.x * 256 + threadIdx.x;
  if (i < N) {
    int o = offsets[i] + blockSums[i >> 10];
    offsets[i] = o;
    cursor[i] = o;
  }
  if (i == 0) offsets[N] = E;
}

__global__ __launch_bounds__(256) void scatter_part(
    const int* __restrict__ row, const int* __restrict__ col,
    const float* __restrict__ val, int* __restrict__ cursor,
    float2* __restrict__ recs, int E, int rpp) {
  int part = blockIdx.x & (NPART - 1);
  int e = (blockIdx.x >> 3) * 256 + threadIdx.x;
  if (e >= E) return;
  int r = row[e];
  unsigned lo = (unsigned)(part * rpp);
  if ((unsigned)(r - lo) >= (unsigned)rpp) return;
  int p = atomicAdd(&cursor[r], 1);
  recs[p] = make_float2(__int_as_float(col[e]), val[e]);
}

// 16-lane group per row; lane owns 4 features.
__global__ __launch_bounds__(256) void spmm_g16(
    const int* __restrict__ off, const float2* __restrict__ recs,
    const float* __restrict__ hin, float* __restrict__ hout, int N) {
  int r = (blockIdx.x * 256 + threadIdx.x) >> 4;
  if (r >= N) return;
  int fp = (threadIdx.x & 15) << 2;
  int i = off[r], end = off[r + 1];
  float4 acc = make_float4(0.f, 0.f, 0.f, 0.f);

  for (; i + 4 <= end; i += 4) {
    float2 e0 = recs[i], e1 = recs[i + 1], e2 = recs[i + 2], e3 = recs[i + 3];
    float4 h0 = *(const float4*)&hin[(size_t)__float_as_int(e0.x) * F + fp];
    float4 h1 = *(const float4*)&hin[(size_t)__float_as_int(e1.x) * F + fp];
    float4 h2 = *(const float4*)&hin[(size_t)__float_as_int(e2.x) * F + fp];
    float4 h3 = *(const float4*)&hin[(size_t)__float_as_int(e3.x) * F + fp];
    acc.x = fmaf(e0.y, h0.x, acc.x); acc.y = fmaf(e0.y, h0.y, acc.y);
    acc.z = fmaf(e0.y, h0.z, acc.z); acc.w = fmaf(e0.y, h0.w, acc.w);
    acc.x = fmaf(e1.y, h1.x, acc.x); acc.y = fmaf(e1.y, h1.y, acc.y);
    acc.z = fmaf(e1.y, h1.z, acc.z); acc.w = fmaf(e1.y, h1.w, acc.w);
    acc.x = fmaf(e2.y, h2.x, acc.x); acc.y = fmaf(e2.y, h2.y, acc.y);
    acc.z = fmaf(e2.y, h2.z, acc.z); acc.w = fmaf(e2.y, h2.w, acc.w);
    acc.x = fmaf(e3.y, h3.x, acc.x); acc.y = fmaf(e3.y, h3.y, acc.y);
    acc.z = fmaf(e3.y, h3.z, acc.z); acc.w = fmaf(e3.y, h3.w, acc.w);
  }
  for (; i < end; ++i) {
    float2 e0 = recs[i];
    float4 h0 = *(const float4*)&hin[(size_t)__float_as_int(e0.x) * F + fp];
    acc.x = fmaf(e0.y, h0.x, acc.x); acc.y = fmaf(e0.y, h0.y, acc.y);
    acc.z = fmaf(e0.y, h0.z, acc.z); acc.w = fmaf(e0.y, h0.w, acc.w);
  }
  *(float4*)&hout[(size_t)r * F + fp] = acc;
}

// out = bias + h0@W0 + h1@W1 + h2@W2 + h3@W3 (h3 lives in out).
// Thread = 4 nodes x 16 outs; block = 256 nodes. W in LDS, reused 4x per read.
__global__ __launch_bounds__(256) void gemm_fused4_v4(
    const float* __restrict__ h0, const float* __restrict__ h1,
    const float* __restrict__ h2, const float* __restrict__ W,
    const float* __restrict__ bias, float* __restrict__ out, int N) {
  __shared__ float Ws[64 * 64];  // 16 KB, one stage at a time
  const float* hs[4] = {h0, h1, h2, out};

  int t = threadIdx.x;
  int oq = t & 3;
  int og = oq << 4;
  int ns = t >> 2;                 // node slot 0..63
  int node0 = blockIdx.x * 256;

  const float4* b4 = (const float4*)bias;
  float4 acc[4][4];
#pragma unroll
  for (int i = 0; i < 4; ++i)
#pragma unroll
    for (int m = 0; m < 4; ++m) acc[i][m] = b4[oq * 4 + m];

#pragma unroll
  for (int s = 0; s < 4; ++s) {
    __syncthreads();  // previous stage's Ws readers done
    const float4* Wg = (const float4*)(W + s * 4096);
#pragma unroll
    for (int i = 0; i < 4; ++i) ((float4*)Ws)[t + i * 256] = Wg[t + i * 256];
    __syncthreads();

    const float4* hr[4];
#pragma unroll
    for (int i = 0; i < 4; ++i) {
      int n = min(node0 + ns + 64 * i, N - 1);
      hr[i] = (const float4*)(hs[s] + (size_t)n * F);
    }

    float4 hc[4], hn[4];
#pragma unroll
    for (int i = 0; i < 4; ++i) hc[i] = hr[i][0];

#pragma unroll 2
    for (int k4 = 0; k4 < 16; ++k4) {
      if (k4 < 15) {
#pragma unroll
        for (int i = 0; i < 4; ++i) hn[i] = hr[i][k4 + 1];
      }
#pragma unroll
      for (int j = 0; j < 4; ++j) {
        const float4* w4 = (const float4*)&Ws[(k4 * 4 + j) * 64 + og];
        float4 w0 = w4[0], w1 = w4[1], w2 = w4[2], w3 = w4[3];
#pragma unroll
        for (int i = 0; i < 4; ++i) {
          float hk = (j == 0) ? hc[i].x : (j == 1) ? hc[i].y
                   : (j == 2) ? hc[i].z : hc[i].w;
          acc[i][0].x = fmaf(hk, w0.x, acc[i][0].x);
          acc[i][0].y = fmaf(hk, w0.y, acc[i][0].y);
          acc[i][0].z = fmaf(hk, w0.z, acc[i][0].z);
          acc[i][0].w = fmaf(hk, w0.w, acc[i][0].w);
          acc[i][1].x = fmaf(hk, w1.x, acc[i][1].x);
          acc[i][1].y = fmaf(hk, w1.y, acc[i][1].y);
          acc[i][1].z = fmaf(hk, w1.z, acc[i][1].z);
          acc[i][1].w = fmaf(hk, w1.w, acc[i][1].w);
          acc[i][2].x = fmaf(hk, w2.x, acc[i][2].x);
          acc[i][2].y = fmaf(hk, w2.y, acc[i][2].y);
          acc[i][2].z = fmaf(hk, w2.z, acc[i][2].z);
          acc[i][2].w = fmaf(hk, w2.w, acc[i][2].w);
          acc[i][3].x = fmaf(hk, w3.x, acc[i][3].x);
          acc[i][3].y = fmaf(hk, w3.y, acc[i][3].y);
          acc[i][3].z = fmaf(hk, w3.z, acc[i][3].z);
          acc[i][3].w = fmaf(hk, w3.w, acc[i][3].w);
        }
      }
      if (k4 < 15) {
#pragma unroll
        for (int i = 0; i < 4; ++i) hc[i] = hn[i];
      }
    }
  }

#pragma unroll
  for (int i = 0; i < 4; ++i) {
    int n = node0 + ns + 64 * i;
    if (n < N) {
      float4* o4 = (float4*)&out[(size_t)n * OUT + og];
      o4[0] = acc[i][0]; o4[1] = acc[i][1]; o4[2] = acc[i][2]; o4[3] = acc[i][3];
    }
  }
}

extern "C" void kernel_launch(void* const* d_in, const int* in_sizes, int n_in,
                              void* d_out, int out_size, void* d_ws, size_t ws_size,
                              hipStream_t stream) {
  const float* x    = (const float*)d_in[0];
  const int*   erow = (const int*)d_in[1];
  const int*   ecol = (const int*)d_in[2];
  const float* eval = (const float*)d_in[3];
  const float* W    = (const float*)d_in[4];
  const float* b    = (const float*)d_in[5];
  float* out = (float*)d_out;

  int N = in_sizes[0] / F;
  int E = in_sizes[1];
  size_t SZ = (size_t)N * F * sizeof(float);
  int nScanBlocks = (N + SCAN_ELEMS - 1) / SCAN_ELEMS;
  int rpp = (N + NPART - 1) / NPART;

  char* p = (char*)d_ws;
  float*  hA     = (float*)p;  p += SZ;
  float*  hB     = (float*)p;  p += SZ;
  float2* recs   = (float2*)p; p += (size_t)E * sizeof(float2);
  int*    counts = (int*)p;    p += (size_t)N * sizeof(int);
  int*    offs   = (int*)p;    p += (size_t)(N + 1) * sizeof(int);
  int*    cursor = (int*)p;    p += (size_t)N * sizeof(int);
  int*    bsums  = (int*)p;    p += (size_t)nScanBlocks * sizeof(int);

  int egrid = (E + 255) / 256;
  int g16grid = ((size_t)N * 16 + 255) / 256;
  int ggrid = (N + 255) / 256;

  // --- CSR build ---
  hipMemsetAsync(counts, 0, (size_t)N * sizeof(int), stream);
  count_part<<<egrid * NPART, 256, 0, stream>>>(erow, counts, E, rpp);
  block_scan<<<nScanBlocks, 256, 0, stream>>>(counts, offs, bsums, N);
  scan_sums<<<1, 64, 0, stream>>>(bsums, nScanBlocks);
  add_offsets<<<(N + 255) / 256, 256, 0, stream>>>(offs, bsums, cursor, N, E);
  scatter_part<<<egrid * NPART, 256, 0, stream>>>(erow, ecol, eval, cursor, recs, E, rpp);

  // --- propagation (h3 -> d_out as scratch) ---
  spmm_g16<<<g16grid, 256, 0, stream>>>(offs, recs, x, hA, N);    // h1
  spmm_g16<<<g16grid, 256, 0, stream>>>(offs, recs, hA, hB, N);   // h2
  spmm_g16<<<g16grid, 256, 0, stream>>>(offs, recs, hB, out, N);  // h3

  gemm_fused4_v4<<<ggrid, 256, 0, stream>>>(x, hA, hB, W, b, out, N);
}